// Round 1
// baseline (293.775 us; speedup 1.0000x reference)
//
#include <hip/hip_runtime.h>

#define H   768
#define Hh  384
#define LL  192
#define BB  4
#define RR  24

// ---------------------------------------------------------------------------
// Kernel 1: all three 768x768x768 fp32 GEMMs (+ stage1 phase A)
//   grid 436 x 256 threads
//   bid < 432 : 64x64 output tile, K=768 in chunks of 16.
//       nt = bid%36, mt = bid/36; sel = nt/12:
//         sel 0: hf  = emb @ W_corr[:H]  + b_corr      -> hfb
//         sel 1: hs  = emb @ W_corr[H:]                -> hsb
//         sel 2: fus = emb @ W_tag[H:]   + relpart(b)  -> fusb
//                (relpart = rel_emb[target_rel[b]] @ W_tag[:H] + b_tag,
//                 recomputed per-block: 49K MAC vs 3.1M MAC main loop)
//   bid >= 432: stage1 phase A for b = bid-432: masked avg pool -> relu
//               hidden (384) -> relh_ws
// ---------------------------------------------------------------------------
__global__ __launch_bounds__(256) void k_main(
    const float* __restrict__ emb, const int* __restrict__ mask,
    const int* __restrict__ target_rel,
    const float* __restrict__ W_relh, const float* __restrict__ b_relh,
    const float* __restrict__ W_corr, const float* __restrict__ b_corr,
    const float* __restrict__ rel_emb, const float* __restrict__ W_tag,
    const float* __restrict__ b_tag,
    float* __restrict__ hfb, float* __restrict__ hsb, float* __restrict__ fusb,
    float* __restrict__ relh_ws)
{
    __shared__ __align__(16) float AsT[16][64];   // AsT[kk][m]
    __shared__ __align__(16) float Bs[16][64];    // Bs[kk][n]
    __shared__ float rps[4][64];
    __shared__ float rbias[64];
    __shared__ float avgs[H];

    const int bid = blockIdx.x;
    const int tid = threadIdx.x;

    if (bid >= 432) {
        // ------------------ stage1 phase A ------------------
        const int b = bid - 432;
        float msum = 0.f;
        for (int l = 0; l < LL; ++l) msum += (float)mask[b * LL + l];
        for (int h = tid; h < H; h += 256) {
            float s = 0.f;
            for (int l = 0; l < LL; ++l)
                s += emb[(size_t)(b * LL + l) * H + h] * (float)mask[b * LL + l];
            avgs[h] = s / msum;
        }
        __syncthreads();
        // relh = relu(avg @ W_relh + b_relh), 384 outputs over 256 threads
        float s1 = 0.f, s2 = 0.f;
        for (int h = 0; h < H; ++h) {
            const float a = avgs[h];
            s1 += a * W_relh[(size_t)h * Hh + tid];
            if (tid < 128) s2 += a * W_relh[(size_t)h * Hh + 256 + tid];
        }
        relh_ws[b * Hh + tid] = fmaxf(s1 + b_relh[tid], 0.f);
        if (tid < 128)
            relh_ws[b * Hh + 256 + tid] = fmaxf(s2 + b_relh[256 + tid], 0.f);
        return;
    }

    // ------------------ GEMM blocks ------------------
    const int nt = bid % 36, mt = bid / 36;
    const int sel = nt / 12;
    const int n0 = (nt % 12) * 64;
    const int m0 = mt * 64;

    const float* Bm;
    float* C;
    if (sel == 0)      { Bm = W_corr;          C = hfb;  }
    else if (sel == 1) { Bm = W_corr + (size_t)H * H; C = hsb; }
    else               { Bm = W_tag  + (size_t)H * H; C = fusb; }

    if (sel == 2) {
        // relpart for this n-slice; m-tile lies within one batch element
        const int b = m0 / LL;
        const float* re = rel_emb + (size_t)target_rel[b] * H;
        const int n = tid & 63, part = tid >> 6;
        float s = 0.f;
        const int h0 = part * LL;
        for (int h = h0; h < h0 + LL; ++h)
            s += re[h] * W_tag[(size_t)h * H + n0 + n];
        rps[part][n] = s;
        __syncthreads();
        if (tid < 64)
            rbias[tid] = b_tag[n0 + tid] + rps[0][tid] + rps[1][tid]
                       + rps[2][tid] + rps[3][tid];
        __syncthreads();
    }

    const int tx = tid & 15, ty = tid >> 4;
    const int arow = tid >> 2, akq = tid & 3;   // A stage: 64 rows x 4 quads
    const int bkk = tid >> 4, bnq = tid & 15;   // B stage: 16 k-rows x 16 quads

    float acc[4][4] = {{0.f}};

    for (int k0 = 0; k0 < H; k0 += 16) {
        const float4 av = *(const float4*)(emb + (size_t)(m0 + arow) * H + k0 + akq * 4);
        AsT[akq * 4 + 0][arow] = av.x;
        AsT[akq * 4 + 1][arow] = av.y;
        AsT[akq * 4 + 2][arow] = av.z;
        AsT[akq * 4 + 3][arow] = av.w;
        *(float4*)&Bs[bkk][bnq * 4] =
            *(const float4*)(Bm + (size_t)(k0 + bkk) * H + n0 + bnq * 4);
        __syncthreads();
#pragma unroll
        for (int kk = 0; kk < 16; ++kk) {
            const float4 a  = *(const float4*)&AsT[kk][ty * 4];
            const float4 b4 = *(const float4*)&Bs[kk][tx * 4];
            acc[0][0] += a.x * b4.x; acc[0][1] += a.x * b4.y;
            acc[0][2] += a.x * b4.z; acc[0][3] += a.x * b4.w;
            acc[1][0] += a.y * b4.x; acc[1][1] += a.y * b4.y;
            acc[1][2] += a.y * b4.z; acc[1][3] += a.y * b4.w;
            acc[2][0] += a.z * b4.x; acc[2][1] += a.z * b4.y;
            acc[2][2] += a.z * b4.z; acc[2][3] += a.z * b4.w;
            acc[3][0] += a.w * b4.x; acc[3][1] += a.w * b4.y;
            acc[3][2] += a.w * b4.z; acc[3][3] += a.w * b4.w;
        }
        __syncthreads();
    }

    float cb[4];
#pragma unroll
    for (int j = 0; j < 4; ++j) {
        cb[j] = (sel == 0) ? b_corr[n0 + tx * 4 + j]
              : (sel == 2) ? rbias[tx * 4 + j] : 0.f;
    }
#pragma unroll
    for (int i = 0; i < 4; ++i) {
        const int m = m0 + ty * 4 + i;
        float4 o;
        o.x = acc[i][0] + cb[0];
        o.y = acc[i][1] + cb[1];
        o.z = acc[i][2] + cb[2];
        o.w = acc[i][3] + cb[3];
        *(float4*)(C + (size_t)m * H + n0 + tx * 4) = o;
    }
}

// ---------------------------------------------------------------------------
// Kernel 2: corres + tag heads + stage1 phase B
//   grid 481 x 256 threads
//   bid < 288 : corres 16(i) x 32(j) tile, 2 outputs/thread, h-chunks of 32
//   288..479  : tag heads, one wave per fusion row (4 rows/block)
//   bid == 480: stage1 final GEMV (4x24)
// ---------------------------------------------------------------------------
__global__ __launch_bounds__(256) void k_tail(
    const float* __restrict__ hfb, const float* __restrict__ hsb,
    const float* __restrict__ fusb, const float* __restrict__ relh_ws,
    const float* __restrict__ W_gc, const float* __restrict__ b_gc,
    const float* __restrict__ W_rj, const float* __restrict__ b_rj,
    const float* __restrict__ W_sub, const float* __restrict__ b_sub,
    const float* __restrict__ W_obj, const float* __restrict__ b_obj,
    float* __restrict__ out)
{
    const int bid = blockIdx.x, tid = threadIdx.x;

    if (bid < 288) {
        // pred_corres[b,i,j] = relu(hf[j,:] + hs[i,:]) . w_gc + b_gc
        // (b_corr already folded into hf)
        __shared__ float hfT[32][34];   // [kk][j], pad 34 -> conflict-free b64 reads
        __shared__ float hsT[32][17];   // [kk][i], pad 17
        __shared__ float wgs[32];
        const int b   = bid / 72;
        const int rem = bid % 72;
        const int i0  = (rem / 6) * 16;
        const int j0  = (rem % 6) * 32;
        const int tx = tid & 15, ty = tid >> 4;
        const int frow = tid >> 3, fq = tid & 7;
        float acc0 = 0.f, acc1 = 0.f;

        for (int hc = 0; hc < H; hc += 32) {
            const float4 fv = *(const float4*)(hfb + (size_t)(b * LL + j0 + frow) * H + hc + fq * 4);
            hfT[fq * 4 + 0][frow] = fv.x;
            hfT[fq * 4 + 1][frow] = fv.y;
            hfT[fq * 4 + 2][frow] = fv.z;
            hfT[fq * 4 + 3][frow] = fv.w;
            if (tid < 128) {
                const float4 sv = *(const float4*)(hsb + (size_t)(b * LL + i0 + frow) * H + hc + fq * 4);
                hsT[fq * 4 + 0][frow] = sv.x;
                hsT[fq * 4 + 1][frow] = sv.y;
                hsT[fq * 4 + 2][frow] = sv.z;
                hsT[fq * 4 + 3][frow] = sv.w;
            }
            if (tid >= 128 && tid < 160) wgs[tid - 128] = W_gc[hc + tid - 128];
            __syncthreads();
#pragma unroll
            for (int kk = 0; kk < 32; ++kk) {
                const float f0 = hfT[kk][tx * 2];
                const float f1 = hfT[kk][tx * 2 + 1];
                const float s  = hsT[kk][ty];
                const float w  = wgs[kk];
                acc0 += fmaxf(f0 + s, 0.f) * w;
                acc1 += fmaxf(f1 + s, 0.f) * w;
            }
            __syncthreads();
        }
        const float bg = b_gc[0];
        float* po = out + 4704 + (size_t)b * LL * LL + (size_t)(i0 + ty) * LL + j0 + tx * 2;
        po[0] = acc0 + bg;
        po[1] = acc1 + bg;
    } else if (bid < 480) {
        // subj/obj tag heads: one wave per row of fusion
        const int wave = tid >> 6, lane = tid & 63;
        const int r = (bid - 288) * 4 + wave;
        float a0 = 0, a1 = 0, a2 = 0, a3 = 0, a4 = 0, a5 = 0;
        for (int h = lane; h < H; h += 64) {
            const float f = fusb[(size_t)r * H + h];
            a0 += f * W_sub[h * 3 + 0];
            a1 += f * W_sub[h * 3 + 1];
            a2 += f * W_sub[h * 3 + 2];
            a3 += f * W_obj[h * 3 + 0];
            a4 += f * W_obj[h * 3 + 1];
            a5 += f * W_obj[h * 3 + 2];
        }
#pragma unroll
        for (int off = 32; off > 0; off >>= 1) {
            a0 += __shfl_down(a0, off);
            a1 += __shfl_down(a1, off);
            a2 += __shfl_down(a2, off);
            a3 += __shfl_down(a3, off);
            a4 += __shfl_down(a4, off);
            a5 += __shfl_down(a5, off);
        }
        if (lane == 0) {
            out[96 + r * 3 + 0]   = a0 + b_sub[0];
            out[96 + r * 3 + 1]   = a1 + b_sub[1];
            out[96 + r * 3 + 2]   = a2 + b_sub[2];
            out[2400 + r * 3 + 0] = a3 + b_obj[0];
            out[2400 + r * 3 + 1] = a4 + b_obj[1];
            out[2400 + r * 3 + 2] = a5 + b_obj[2];
        }
    } else {
        // stage1 phase B: stage1 = relh @ W_rj + b_rj  (4 x 24)
        if (tid < 96) {
            const int b = tid / 24, rj = tid % 24;
            float s = b_rj[rj];
            for (int h = 0; h < Hh; ++h)
                s += relh_ws[b * Hh + h] * W_rj[h * RR + rj];
            out[b * RR + rj] = s;
        }
    }
}

extern "C" void kernel_launch(void* const* d_in, const int* in_sizes, int n_in,
                              void* d_out, int out_size, void* d_ws, size_t ws_size,
                              hipStream_t stream) {
    const float* emb    = (const float*)d_in[0];
    const int*   mask   = (const int*)d_in[1];
    const int*   trel   = (const int*)d_in[2];
    const float* W_relh = (const float*)d_in[3];
    const float* b_relh = (const float*)d_in[4];
    const float* W_rj   = (const float*)d_in[5];
    const float* b_rj   = (const float*)d_in[6];
    const float* W_corr = (const float*)d_in[7];
    const float* b_corr = (const float*)d_in[8];
    const float* W_gc   = (const float*)d_in[9];
    const float* b_gc   = (const float*)d_in[10];
    const float* relemb = (const float*)d_in[11];
    const float* W_tag  = (const float*)d_in[12];
    const float* b_tag  = (const float*)d_in[13];
    const float* W_sub  = (const float*)d_in[14];
    const float* b_sub  = (const float*)d_in[15];
    const float* W_obj  = (const float*)d_in[16];
    const float* b_obj  = (const float*)d_in[17];

    float* out = (float*)d_out;
    float* ws  = (float*)d_ws;
    float* hfb     = ws;                       // 768*768
    float* hsb     = ws + (size_t)H * H;       // 768*768
    float* fusb    = ws + (size_t)2 * H * H;   // 768*768
    float* relh_ws = ws + (size_t)3 * H * H;   // 4*384

    k_main<<<436, 256, 0, stream>>>(emb, mask, trel, W_relh, b_relh,
                                    W_corr, b_corr, relemb, W_tag, b_tag,
                                    hfb, hsb, fusb, relh_ws);
    k_tail<<<481, 256, 0, stream>>>(hfb, hsb, fusb, relh_ws,
                                    W_gc, b_gc, W_rj, b_rj,
                                    W_sub, b_sub, W_obj, b_obj, out);
}

// Round 2
// 101.738 us; speedup vs baseline: 2.8876x; 2.8876x over previous
//
#include <hip/hip_runtime.h>

#define H   768
#define Hh  384
#define LL  192
#define RR  24

// ---------------------------------------------------------------------------
// Kernel 0: masked average pool.  grid 24 = 4(b) x 6(h-chunks of 128)
// avg_ws[b*H + h] = sum_l emb[b,l,h]*mask[b,l] / sum_l mask[b,l]
// ---------------------------------------------------------------------------
__global__ __launch_bounds__(256) void k_pre(
    const float* __restrict__ emb, const int* __restrict__ mask,
    float* __restrict__ avg_ws)
{
    __shared__ float msk[LL];
    __shared__ float part[32];
    __shared__ float msumS;
    __shared__ float4 red4[8][32];

    const int tid = threadIdx.x;
    const int b  = blockIdx.x / 6;
    const int h0 = (blockIdx.x % 6) * 128;
    const int tx = tid & 31, ty = tid >> 5;

    if (tid < LL) msk[tid] = (float)mask[b * LL + tid];
    __syncthreads();
    if (tid < 32) {
        float s = 0.f;
        for (int k = tid; k < LL; k += 32) s += msk[k];
        part[tid] = s;
    }
    __syncthreads();
    if (tid == 0) {
        float s = 0.f;
        for (int k = 0; k < 32; ++k) s += part[k];
        msumS = s;
    }

    float4 acc = make_float4(0.f, 0.f, 0.f, 0.f);
    for (int l = ty; l < LL; l += 8) {
        const float m = msk[l];
        const float4 v = *(const float4*)(emb + (size_t)(b * LL + l) * H + h0 + tx * 4);
        acc.x += v.x * m; acc.y += v.y * m; acc.z += v.z * m; acc.w += v.w * m;
    }
    red4[ty][tx] = acc;
    __syncthreads();           // also orders msumS write before reads below
    if (tid < 32) {
        float4 s = red4[0][tid];
#pragma unroll
        for (int r = 1; r < 8; ++r) {
            s.x += red4[r][tid].x; s.y += red4[r][tid].y;
            s.z += red4[r][tid].z; s.w += red4[r][tid].w;
        }
        const float inv = 1.f / msumS;
        s.x *= inv; s.y *= inv; s.z *= inv; s.w *= inv;
        *(float4*)(avg_ws + (size_t)b * H + h0 + tid * 4) = s;
    }
}

// ---------------------------------------------------------------------------
// Kernel 1: three 768x768x768 fp32 GEMMs + relh GEMV
//   grid 456 x 256 threads
//   bid < 432 : 64x64 output tile, K chunks of 16, reg-prefetch double-buffer
//   bid >= 432: relh[b] = relu(avg @ W_relh + b_relh), 24 blocks (4b x 6 o-chunks)
// ---------------------------------------------------------------------------
__global__ __launch_bounds__(256) void k_main(
    const float* __restrict__ emb, const int* __restrict__ target_rel,
    const float* __restrict__ W_relh, const float* __restrict__ b_relh,
    const float* __restrict__ W_corr, const float* __restrict__ b_corr,
    const float* __restrict__ rel_emb, const float* __restrict__ W_tag,
    const float* __restrict__ b_tag, const float* __restrict__ avg_ws,
    float* __restrict__ hfb, float* __restrict__ hsb, float* __restrict__ fusb,
    float* __restrict__ relh_ws)
{
    __shared__ __align__(16) float AsT[16][68];   // pad 68: stores 2-way (free)
    __shared__ __align__(16) float Bs[16][64];
    __shared__ float rps[4][64];
    __shared__ float rbias[64];

    const int bid = blockIdx.x;
    const int tid = threadIdx.x;

    if (bid >= 432) {
        // ---- relh GEMV: [4,768] @ [768,384] ----
        __shared__ float avgS[H];
        __shared__ float redr[4][64];
        const int rb = bid - 432;
        const int b  = rb / 6;
        const int o0 = (rb % 6) * 64;
        const int tx = tid & 63, ty = tid >> 6;
        for (int i = tid; i < H; i += 256) avgS[i] = avg_ws[(size_t)b * H + i];
        __syncthreads();
        float s = 0.f;
        for (int k = ty; k < H; k += 4)
            s += avgS[k] * W_relh[(size_t)k * Hh + o0 + tx];
        redr[ty][tx] = s;
        __syncthreads();
        if (ty == 0) {
            float r = redr[0][tx] + redr[1][tx] + redr[2][tx] + redr[3][tx];
            relh_ws[(size_t)b * Hh + o0 + tx] = fmaxf(r + b_relh[o0 + tx], 0.f);
        }
        return;
    }

    // ------------------ GEMM blocks ------------------
    const int nt = bid % 36, mt = bid / 36;
    const int sel = nt / 12;
    const int n0 = (nt % 12) * 64;
    const int m0 = mt * 64;

    const float* Bm;
    float* C;
    if (sel == 0)      { Bm = W_corr;                 C = hfb;  }
    else if (sel == 1) { Bm = W_corr + (size_t)H * H; C = hsb;  }
    else               { Bm = W_tag  + (size_t)H * H; C = fusb; }

    if (sel == 2) {
        const int b = m0 / LL;
        const float* re = rel_emb + (size_t)target_rel[b] * H;
        const int n = tid & 63, part = tid >> 6;
        float s = 0.f;
        const int h0 = part * LL;
        for (int h = h0; h < h0 + LL; ++h)
            s += re[h] * W_tag[(size_t)h * H + n0 + n];
        rps[part][n] = s;
        __syncthreads();
        if (tid < 64)
            rbias[tid] = b_tag[n0 + tid] + rps[0][tid] + rps[1][tid]
                       + rps[2][tid] + rps[3][tid];
        __syncthreads();
    }

    const int tx = tid & 15, ty = tid >> 4;
    const int arow = tid >> 2, akq = tid & 3;   // A stage: 64 rows x 4 quads
    const int bkk = tid >> 4, bnq = tid & 15;   // B stage: 16 k-rows x 16 quads

    const float* Aptr = emb + (size_t)(m0 + arow) * H + akq * 4;
    const float* Bptr = Bm + (size_t)bkk * H + n0 + bnq * 4;

    float acc[4][4] = {{0.f}};
    float4 av = *(const float4*)Aptr;
    float4 bv = *(const float4*)Bptr;

    for (int k0 = 0; k0 < H; k0 += 16) {
        AsT[akq * 4 + 0][arow] = av.x;
        AsT[akq * 4 + 1][arow] = av.y;
        AsT[akq * 4 + 2][arow] = av.z;
        AsT[akq * 4 + 3][arow] = av.w;
        *(float4*)&Bs[bkk][bnq * 4] = bv;
        __syncthreads();
        if (k0 + 16 < H) {                      // prefetch next tile
            av = *(const float4*)(Aptr + k0 + 16);
            bv = *(const float4*)(Bptr + (size_t)(k0 + 16) * H);
        }
#pragma unroll
        for (int kk = 0; kk < 16; ++kk) {
            const float4 a  = *(const float4*)&AsT[kk][ty * 4];
            const float4 b4 = *(const float4*)&Bs[kk][tx * 4];
            acc[0][0] += a.x * b4.x; acc[0][1] += a.x * b4.y;
            acc[0][2] += a.x * b4.z; acc[0][3] += a.x * b4.w;
            acc[1][0] += a.y * b4.x; acc[1][1] += a.y * b4.y;
            acc[1][2] += a.y * b4.z; acc[1][3] += a.y * b4.w;
            acc[2][0] += a.z * b4.x; acc[2][1] += a.z * b4.y;
            acc[2][2] += a.z * b4.z; acc[2][3] += a.z * b4.w;
            acc[3][0] += a.w * b4.x; acc[3][1] += a.w * b4.y;
            acc[3][2] += a.w * b4.z; acc[3][3] += a.w * b4.w;
        }
        __syncthreads();
    }

    float cb[4];
#pragma unroll
    for (int j = 0; j < 4; ++j) {
        cb[j] = (sel == 0) ? b_corr[n0 + tx * 4 + j]
              : (sel == 2) ? rbias[tx * 4 + j] : 0.f;
    }
#pragma unroll
    for (int i = 0; i < 4; ++i) {
        const int m = m0 + ty * 4 + i;
        float4 o;
        o.x = acc[i][0] + cb[0];
        o.y = acc[i][1] + cb[1];
        o.z = acc[i][2] + cb[2];
        o.w = acc[i][3] + cb[3];
        *(float4*)(C + (size_t)m * H + n0 + tx * 4) = o;
    }
}

// ---------------------------------------------------------------------------
// Kernel 2: corres + tag heads + stage1 phase B
//   grid 481 x 256 threads
// ---------------------------------------------------------------------------
__global__ __launch_bounds__(256) void k_tail(
    const float* __restrict__ hfb, const float* __restrict__ hsb,
    const float* __restrict__ fusb, const float* __restrict__ relh_ws,
    const float* __restrict__ W_gc, const float* __restrict__ b_gc,
    const float* __restrict__ W_rj, const float* __restrict__ b_rj,
    const float* __restrict__ W_sub, const float* __restrict__ b_sub,
    const float* __restrict__ W_obj, const float* __restrict__ b_obj,
    float* __restrict__ out)
{
    const int bid = blockIdx.x, tid = threadIdx.x;

    if (bid < 288) {
        // pred_corres[b,i,j] = relu(hf[j,:] + hs[i,:]) . w_gc + b_gc
        __shared__ float hfT[32][34];
        __shared__ float hsT[32][17];
        __shared__ float wgs[32];
        const int b   = bid / 72;
        const int rem = bid % 72;
        const int i0  = (rem / 6) * 16;
        const int j0  = (rem % 6) * 32;
        const int tx = tid & 15, ty = tid >> 4;
        const int frow = tid >> 3, fq = tid & 7;
        float acc0 = 0.f, acc1 = 0.f;

        for (int hc = 0; hc < H; hc += 32) {
            const float4 fv = *(const float4*)(hfb + (size_t)(b * LL + j0 + frow) * H + hc + fq * 4);
            hfT[fq * 4 + 0][frow] = fv.x;
            hfT[fq * 4 + 1][frow] = fv.y;
            hfT[fq * 4 + 2][frow] = fv.z;
            hfT[fq * 4 + 3][frow] = fv.w;
            if (tid < 128) {
                const float4 sv = *(const float4*)(hsb + (size_t)(b * LL + i0 + frow) * H + hc + fq * 4);
                hsT[fq * 4 + 0][frow] = sv.x;
                hsT[fq * 4 + 1][frow] = sv.y;
                hsT[fq * 4 + 2][frow] = sv.z;
                hsT[fq * 4 + 3][frow] = sv.w;
            }
            if (tid >= 128 && tid < 160) wgs[tid - 128] = W_gc[hc + tid - 128];
            __syncthreads();
#pragma unroll
            for (int kk = 0; kk < 32; ++kk) {
                const float2 f = *(const float2*)&hfT[kk][tx * 2];
                const float s  = hsT[kk][ty];
                const float w  = wgs[kk];
                acc0 += fmaxf(f.x + s, 0.f) * w;
                acc1 += fmaxf(f.y + s, 0.f) * w;
            }
            __syncthreads();
        }
        const float bg = b_gc[0];
        float* po = out + 4704 + (size_t)b * LL * LL + (size_t)(i0 + ty) * LL + j0 + tx * 2;
        po[0] = acc0 + bg;
        po[1] = acc1 + bg;
    } else if (bid < 480) {
        // subj/obj tag heads: one wave per row of fusion
        const int wave = tid >> 6, lane = tid & 63;
        const int r = (bid - 288) * 4 + wave;
        float a0 = 0, a1 = 0, a2 = 0, a3 = 0, a4 = 0, a5 = 0;
        for (int h = lane; h < H; h += 64) {
            const float f = fusb[(size_t)r * H + h];
            a0 += f * W_sub[h * 3 + 0];
            a1 += f * W_sub[h * 3 + 1];
            a2 += f * W_sub[h * 3 + 2];
            a3 += f * W_obj[h * 3 + 0];
            a4 += f * W_obj[h * 3 + 1];
            a5 += f * W_obj[h * 3 + 2];
        }
#pragma unroll
        for (int off = 32; off > 0; off >>= 1) {
            a0 += __shfl_down(a0, off);
            a1 += __shfl_down(a1, off);
            a2 += __shfl_down(a2, off);
            a3 += __shfl_down(a3, off);
            a4 += __shfl_down(a4, off);
            a5 += __shfl_down(a5, off);
        }
        if (lane == 0) {
            out[96 + r * 3 + 0]   = a0 + b_sub[0];
            out[96 + r * 3 + 1]   = a1 + b_sub[1];
            out[96 + r * 3 + 2]   = a2 + b_sub[2];
            out[2400 + r * 3 + 0] = a3 + b_obj[0];
            out[2400 + r * 3 + 1] = a4 + b_obj[1];
            out[2400 + r * 3 + 2] = a5 + b_obj[2];
        }
    } else {
        // stage1 phase B: stage1 = relh @ W_rj + b_rj  (4 x 24)
        if (tid < 96) {
            const int b = tid / 24, rj = tid % 24;
            float s = b_rj[rj];
            for (int h = 0; h < Hh; ++h)
                s += relh_ws[b * Hh + h] * W_rj[h * RR + rj];
            out[b * RR + rj] = s;
        }
    }
}

extern "C" void kernel_launch(void* const* d_in, const int* in_sizes, int n_in,
                              void* d_out, int out_size, void* d_ws, size_t ws_size,
                              hipStream_t stream) {
    const float* emb    = (const float*)d_in[0];
    const int*   mask   = (const int*)d_in[1];
    const int*   trel   = (const int*)d_in[2];
    const float* W_relh = (const float*)d_in[3];
    const float* b_relh = (const float*)d_in[4];
    const float* W_rj   = (const float*)d_in[5];
    const float* b_rj   = (const float*)d_in[6];
    const float* W_corr = (const float*)d_in[7];
    const float* b_corr = (const float*)d_in[8];
    const float* W_gc   = (const float*)d_in[9];
    const float* b_gc   = (const float*)d_in[10];
    const float* relemb = (const float*)d_in[11];
    const float* W_tag  = (const float*)d_in[12];
    const float* b_tag  = (const float*)d_in[13];
    const float* W_sub  = (const float*)d_in[14];
    const float* b_sub  = (const float*)d_in[15];
    const float* W_obj  = (const float*)d_in[16];
    const float* b_obj  = (const float*)d_in[17];

    float* out = (float*)d_out;
    float* ws  = (float*)d_ws;
    float* hfb     = ws;                            // 768*768
    float* hsb     = ws + (size_t)H * H;            // 768*768
    float* fusb    = ws + (size_t)2 * H * H;        // 768*768
    float* relh_ws = ws + (size_t)3 * H * H;        // 4*384
    float* avg_ws  = relh_ws + 4 * Hh;              // 4*768

    k_pre<<<24, 256, 0, stream>>>(emb, mask, avg_ws);
    k_main<<<456, 256, 0, stream>>>(emb, trel, W_relh, b_relh,
                                    W_corr, b_corr, relemb, W_tag, b_tag,
                                    avg_ws, hfb, hsb, fusb, relh_ws);
    k_tail<<<481, 256, 0, stream>>>(hfb, hsb, fusb, relh_ws,
                                    W_gc, b_gc, W_rj, b_rj,
                                    W_sub, b_sub, W_obj, b_obj, out);
}